// Round 1
// baseline (229.667 us; speedup 1.0000x reference)
//
#include <hip/hip_runtime.h>
#include <hip/hip_bf16.h>

#define B_   4096
#define D_   512
#define TB_  8192        // 2B rows
#define BM   128
#define BK   64
#define INV_T 14.285714285714286f   // 1/0.07

typedef __attribute__((ext_vector_type(8))) short bf16x8;
typedef __attribute__((ext_vector_type(4))) float f32x4;
typedef __attribute__((ext_vector_type(8))) unsigned short ushort8;

// async global->LDS, 16B per lane; LDS dest is wave-uniform base + lane*16
#define GLOAD_LDS16(gp, lp)                                                        \
  __builtin_amdgcn_global_load_lds((const __attribute__((address_space(1))) void*)(gp), \
                                   (__attribute__((address_space(3))) void*)(lp),  \
                                   16, 0, 0)

__device__ __forceinline__ unsigned short f2bf(float f) {
  unsigned int x = __float_as_uint(f);
  x += 0x7fffu + ((x >> 16) & 1u);   // round-to-nearest-even
  return (unsigned short)(x >> 16);
}

// ---------------------------------------------------------------------------
// Kernel 1: concat+cast fp32 -> bf16 (E[8192][512]), zero L[8192] and out[0].
// 8 elems/thread; concat is linear since rows are contiguous.
// ---------------------------------------------------------------------------
__global__ void ntx_prep(const float* __restrict__ a, const float* __restrict__ b,
                         unsigned short* __restrict__ E, float* __restrict__ L,
                         float* __restrict__ out) {
  int t = blockIdx.x * blockDim.x + threadIdx.x;      // 0..524287
  int i = t * 8;
  const float* src = (i < B_ * D_) ? (a + i) : (b + (i - B_ * D_));
  float4 v0 = ((const float4*)src)[0];
  float4 v1 = ((const float4*)src)[1];
  ushort8 o;
  o[0] = f2bf(v0.x); o[1] = f2bf(v0.y); o[2] = f2bf(v0.z); o[3] = f2bf(v0.w);
  o[4] = f2bf(v1.x); o[5] = f2bf(v1.y); o[6] = f2bf(v1.z); o[7] = f2bf(v1.w);
  *(ushort8*)(E + i) = o;
  if (t < TB_) L[t] = 0.0f;
  if (t == 0)  out[0] = 0.0f;
}

// ---------------------------------------------------------------------------
// Kernel 2: fused sim + exp row-sum.
// Tile 128x128, BK=64, 4 waves (2x2), mfma_f32_16x16x32_bf16, acc 4x4 / wave.
// LDS st-16x32-style XOR swizzle (chunk ^= row&7), applied on BOTH the
// global source address (linear global_load_lds dest) and the ds_read.
// Epilogue: e = (gr==gc) ? 0 : exp(acc/T); per-row sum over the tile's 128
// cols via in-lane n-sum + 16-lane shfl_xor reduce; atomicAdd into L[row].
// ---------------------------------------------------------------------------
__global__ __launch_bounds__(256, 2)
void ntx_sim(const unsigned short* __restrict__ E, float* __restrict__ L) {
  __shared__ unsigned short As[BM * BK];   // 16 KB, swizzled chunk layout
  __shared__ unsigned short Bs[BM * BK];   // 16 KB

  const int tid  = threadIdx.x;
  const int lane = tid & 63;
  const int wave = tid >> 6;
  const int wr   = wave >> 1;       // wave row (0..1) -> 64-row half
  const int wc   = wave & 1;        // wave col (0..1) -> 64-col half
  const int llo  = lane & 15;
  const int lhi  = lane >> 4;
  const int rowTile = blockIdx.y * BM;
  const int colTile = blockIdx.x * BM;

  f32x4 acc[4][4] = {};

  // --- staging address precompute (chunk = 16B = 8 bf16) ---
  // tile is 128 rows x 8 chunks; thread t handles chunk ch = tid + i*256
  size_t offA[4], offB[4];
  unsigned short* lA[4];
  unsigned short* lB[4];
#pragma unroll
  for (int i = 0; i < 4; ++i) {
    int ch = tid + i * 256;
    int r  = ch >> 3, cc = ch & 7;
    int sc = ((cc ^ (r & 7)) << 3);           // pre-swizzled source chunk col
    offA[i] = (size_t)(rowTile + r) * D_ + sc;
    offB[i] = (size_t)(colTile + r) * D_ + sc;
    lA[i] = As + (size_t)(i * 256 + wave * 64) * 8;
    lB[i] = Bs + (size_t)(i * 256 + wave * 64) * 8;
  }

  // --- fragment LDS pointers (swizzled on read with the same involution) ---
  const bf16x8* pa[2][4];
  const bf16x8* pb[2][4];
#pragma unroll
  for (int ks = 0; ks < 2; ++ks) {
#pragma unroll
    for (int m = 0; m < 4; ++m) {
      int chc = ks * 4 + lhi;                 // logical chunk col 0..7
      int ra  = wr * 64 + m * 16 + llo;       // A row (lane&15 = M row)
      pa[ks][m] = (const bf16x8*)(As + ((size_t)ra * 8 + (chc ^ (ra & 7))) * 8);
      int rb  = wc * 64 + m * 16 + llo;       // B row in E (sim col)
      pb[ks][m] = (const bf16x8*)(Bs + ((size_t)rb * 8 + (chc ^ (rb & 7))) * 8);
    }
  }

  for (int k0 = 0; k0 < D_; k0 += BK) {
#pragma unroll
    for (int i = 0; i < 4; ++i) {
      GLOAD_LDS16(E + offA[i] + k0, lA[i]);
      GLOAD_LDS16(E + offB[i] + k0, lB[i]);
    }
    __syncthreads();   // drains vmcnt: tiles resident
#pragma unroll
    for (int ks = 0; ks < 2; ++ks) {
      bf16x8 af[4], bg[4];
#pragma unroll
      for (int m = 0; m < 4; ++m) af[m] = *pa[ks][m];
#pragma unroll
      for (int n = 0; n < 4; ++n) bg[n] = *pb[ks][n];
#pragma unroll
      for (int m = 0; m < 4; ++m)
#pragma unroll
        for (int n = 0; n < 4; ++n)
          acc[m][n] = __builtin_amdgcn_mfma_f32_16x16x32_bf16(af[m], bg[n], acc[m][n], 0, 0, 0);
    }
    __syncthreads();   // protect LDS before next staging
  }

  // --- epilogue: e = exp(s/T) masked on diag; row-sum over 128 tile cols ---
  // C/D layout: col = lane&15, row = (lane>>4)*4 + reg   [m89-verified]
#pragma unroll
  for (int m = 0; m < 4; ++m) {
    float rs[4] = {0.f, 0.f, 0.f, 0.f};
#pragma unroll
    for (int n = 0; n < 4; ++n) {
      int gc = colTile + wc * 64 + n * 16 + llo;
#pragma unroll
      for (int j = 0; j < 4; ++j) {
        int gr = rowTile + wr * 64 + m * 16 + lhi * 4 + j;
        float s = acc[m][n][j] * INV_T;
        rs[j] += (gr == gc) ? 0.0f : __expf(s);
      }
    }
#pragma unroll
    for (int j = 0; j < 4; ++j) {
      float v = rs[j];
      v += __shfl_xor(v, 1);
      v += __shfl_xor(v, 2);
      v += __shfl_xor(v, 4);
      v += __shfl_xor(v, 8);
      if (llo == 0) {
        int gr = rowTile + wr * 64 + m * 16 + lhi * 4 + j;
        atomicAdd(&L[gr], v);
      }
    }
  }
}

// ---------------------------------------------------------------------------
// Kernel 3: one wave per row: pos_i = <emb[i], emb[partner]>/T in fp32,
// nll = log(L[i]) - pos, atomic mean into out.
// ---------------------------------------------------------------------------
__global__ void ntx_fin(const float* __restrict__ a, const float* __restrict__ b,
                        const float* __restrict__ L, float* __restrict__ out) {
  int row  = blockIdx.x * 4 + (threadIdx.x >> 6);
  int lane = threadIdx.x & 63;
  const float* x = (row < B_) ? (a + (size_t)row * D_) : (b + (size_t)(row - B_) * D_);
  int p = (row < B_) ? row + B_ : row - B_;
  const float* y = (p < B_) ? (a + (size_t)p * D_) : (b + (size_t)(p - B_) * D_);
  const float4* x4 = (const float4*)(x + lane * 8);
  const float4* y4 = (const float4*)(y + lane * 8);
  float4 xa = x4[0], xb = x4[1], ya = y4[0], yb = y4[1];
  float s = xa.x * ya.x + xa.y * ya.y + xa.z * ya.z + xa.w * ya.w
          + xb.x * yb.x + xb.y * yb.y + xb.z * yb.z + xb.w * yb.w;
#pragma unroll
  for (int off = 1; off < 64; off <<= 1) s += __shfl_xor(s, off);
  if (lane == 0) {
    float nll = __logf(L[row]) - s * INV_T;
    atomicAdd(out, nll * (1.0f / TB_));
  }
}

// ---------------------------------------------------------------------------
extern "C" void kernel_launch(void* const* d_in, const int* in_sizes, int n_in,
                              void* d_out, int out_size, void* d_ws, size_t ws_size,
                              hipStream_t stream) {
  const float* e1 = (const float*)d_in[0];
  const float* e2 = (const float*)d_in[1];
  float* out = (float*)d_out;
  unsigned short* E = (unsigned short*)d_ws;                       // 8 MB bf16
  float* L = (float*)((char*)d_ws + (size_t)TB_ * D_ * 2);         // 32 KB

  ntx_prep<<<2048, 256, 0, stream>>>(e1, e2, E, L, out);
  dim3 grid(TB_ / BM, TB_ / BM);                                   // 64 x 64
  ntx_sim<<<grid, 256, 0, stream>>>(E, L);
  ntx_fin<<<TB_ / 4, 256, 0, stream>>>(e1, e2, L, out);
}

// Round 2
// 78.011 us; speedup vs baseline: 2.9440x; 2.9440x over previous
//
#include <hip/hip_runtime.h>
#include <hip/hip_bf16.h>

#define B_   4096
#define D_   512
#define TB_  8192        // 2B rows
#define BM   128
#define BK   64
#define NTILE 64         // TB_/BM
#define NTRI  2080       // NTILE*(NTILE+1)/2
#define INV_T 14.285714285714286f   // 1/0.07

typedef __attribute__((ext_vector_type(8))) short bf16x8;
typedef __attribute__((ext_vector_type(4))) float f32x4;
typedef __attribute__((ext_vector_type(8))) unsigned short ushort8;

// async global->LDS, 16B per lane; LDS dest is wave-uniform base + lane*16
#define GLOAD_LDS16(gp, lp)                                                        \
  __builtin_amdgcn_global_load_lds((const __attribute__((address_space(1))) void*)(gp), \
                                   (__attribute__((address_space(3))) void*)(lp),  \
                                   16, 0, 0)

__device__ __forceinline__ unsigned short f2bf(float f) {
  unsigned int x = __float_as_uint(f);
  x += 0x7fffu + ((x >> 16) & 1u);   // round-to-nearest-even
  return (unsigned short)(x >> 16);
}

// ---------------------------------------------------------------------------
// Kernel 1: concat+cast fp32 -> bf16 (E[8192][512]), zero L[8192].
// ---------------------------------------------------------------------------
__global__ void ntx_prep(const float* __restrict__ a, const float* __restrict__ b,
                         unsigned short* __restrict__ E, float* __restrict__ L) {
  int t = blockIdx.x * blockDim.x + threadIdx.x;      // 0..524287
  int i = t * 8;
  const float* src = (i < B_ * D_) ? (a + i) : (b + (i - B_ * D_));
  float4 v0 = ((const float4*)src)[0];
  float4 v1 = ((const float4*)src)[1];
  ushort8 o;
  o[0] = f2bf(v0.x); o[1] = f2bf(v0.y); o[2] = f2bf(v0.z); o[3] = f2bf(v0.w);
  o[4] = f2bf(v1.x); o[5] = f2bf(v1.y); o[6] = f2bf(v1.z); o[7] = f2bf(v1.w);
  *(ushort8*)(E + i) = o;
  if (t < TB_) L[t] = 0.0f;
}

// ---------------------------------------------------------------------------
// Kernel 2: fused sim + exp row-sum, TRIANGULAR tiles only (sim symmetric).
// Off-diagonal tile (i<j): row-sums -> L[row block i], col-sums -> L[col
// block j] (the transposed tile's row-sums). Diagonal tile: row-sums with
// diag mask. 128x128 tile, BK=64, 4 waves 2x2, mfma_f32_16x16x32_bf16.
// LDS XOR swizzle (chunk ^= row&7) on BOTH global source and ds_read.
// ---------------------------------------------------------------------------
__global__ __launch_bounds__(256, 2)
void ntx_sim(const unsigned short* __restrict__ E, float* __restrict__ L) {
  __shared__ unsigned short As[BM * BK];   // 16 KB, swizzled chunk layout
  __shared__ unsigned short Bs[BM * BK];   // 16 KB

  // --- decode triangular tile index t -> (i, j), i<=j ---
  const int t = blockIdx.x;
  int ti = (int)((129.0f - sqrtf(16641.0f - 8.0f * (float)t)) * 0.5f);
  while (ti * (129 - ti) / 2 > t) --ti;
  while ((ti + 1) * (128 - ti) / 2 <= t) ++ti;   // f(ti+1) = (ti+1)*(129-ti-1)/2
  const int tj = ti + (t - ti * (129 - ti) / 2);
  const int rowTile = ti * BM;
  const int colTile = tj * BM;
  const bool diag = (ti == tj);

  const int tid  = threadIdx.x;
  const int lane = tid & 63;
  const int wave = tid >> 6;
  const int wr   = wave >> 1;       // wave row (0..1) -> 64-row half
  const int wc   = wave & 1;        // wave col (0..1) -> 64-col half
  const int llo  = lane & 15;
  const int lhi  = lane >> 4;

  f32x4 acc[4][4] = {};

  // --- staging address precompute (chunk = 16B = 8 bf16) ---
  size_t offA[4], offB[4];
  unsigned short* lA[4];
  unsigned short* lB[4];
#pragma unroll
  for (int i = 0; i < 4; ++i) {
    int ch = tid + i * 256;
    int r  = ch >> 3, cc = ch & 7;
    int sc = ((cc ^ (r & 7)) << 3);           // pre-swizzled source chunk col
    offA[i] = (size_t)(rowTile + r) * D_ + sc;
    offB[i] = (size_t)(colTile + r) * D_ + sc;
    lA[i] = As + (size_t)(i * 256 + wave * 64) * 8;
    lB[i] = Bs + (size_t)(i * 256 + wave * 64) * 8;
  }

  // --- fragment LDS pointers (same involution on read) ---
  const bf16x8* pa[2][4];
  const bf16x8* pb[2][4];
#pragma unroll
  for (int ks = 0; ks < 2; ++ks) {
#pragma unroll
    for (int m = 0; m < 4; ++m) {
      int chc = ks * 4 + lhi;                 // logical chunk col 0..7
      int ra  = wr * 64 + m * 16 + llo;       // A row (lane&15 = M row)
      pa[ks][m] = (const bf16x8*)(As + ((size_t)ra * 8 + (chc ^ (ra & 7))) * 8);
      int rb  = wc * 64 + m * 16 + llo;       // B row in E (sim col)
      pb[ks][m] = (const bf16x8*)(Bs + ((size_t)rb * 8 + (chc ^ (rb & 7))) * 8);
    }
  }

  for (int k0 = 0; k0 < D_; k0 += BK) {
#pragma unroll
    for (int i = 0; i < 4; ++i) {
      GLOAD_LDS16(E + offA[i] + k0, lA[i]);
      GLOAD_LDS16(E + offB[i] + k0, lB[i]);
    }
    __syncthreads();   // drains vmcnt: tiles resident
#pragma unroll
    for (int ks = 0; ks < 2; ++ks) {
      bf16x8 af[4], bg[4];
#pragma unroll
      for (int m = 0; m < 4; ++m) af[m] = *pa[ks][m];
#pragma unroll
      for (int n = 0; n < 4; ++n) bg[n] = *pb[ks][n];
#pragma unroll
      for (int m = 0; m < 4; ++m)
#pragma unroll
        for (int n = 0; n < 4; ++n)
          acc[m][n] = __builtin_amdgcn_mfma_f32_16x16x32_bf16(af[m], bg[n], acc[m][n], 0, 0, 0);
    }
    __syncthreads();   // protect LDS before next staging
  }

  // --- epilogue ---
  // C/D layout: col = lane&15, row = (lane>>4)*4 + reg   [m89-verified]
  float cs[4] = {0.f, 0.f, 0.f, 0.f};       // per-n column partial (in-lane)
#pragma unroll
  for (int m = 0; m < 4; ++m) {
    float rs[4] = {0.f, 0.f, 0.f, 0.f};
#pragma unroll
    for (int n = 0; n < 4; ++n) {
      int gc = colTile + wc * 64 + n * 16 + llo;
#pragma unroll
      for (int jj = 0; jj < 4; ++jj) {
        int gr = rowTile + wr * 64 + m * 16 + lhi * 4 + jj;
        float e = __expf(acc[m][n][jj] * INV_T);
        e = (diag && gr == gc) ? 0.0f : e;
        rs[jj] += e;
        cs[n]  += e;
      }
    }
#pragma unroll
    for (int jj = 0; jj < 4; ++jj) {
      float v = rs[jj];
      v += __shfl_xor(v, 1);
      v += __shfl_xor(v, 2);
      v += __shfl_xor(v, 4);
      v += __shfl_xor(v, 8);
      if (llo == 0) {
        int gr = rowTile + wr * 64 + m * 16 + lhi * 4 + jj;
        atomicAdd(&L[gr], v);
      }
    }
  }
  if (!diag) {
    // column sums = row sums of the mirrored tile (j,i)
#pragma unroll
    for (int n = 0; n < 4; ++n) {
      float v = cs[n];
      v += __shfl_xor(v, 16);
      v += __shfl_xor(v, 32);
      if (lhi == 0) {
        int gc = colTile + wc * 64 + n * 16 + llo;
        atomicAdd(&L[gc], v);
      }
    }
  }
}

// ---------------------------------------------------------------------------
// Kernel 3: one wave per row: pos = <emb[i],emb[partner]>/T fp32;
// nll = log(L) - pos; per-block partial sum (NO same-address atomics).
// ---------------------------------------------------------------------------
__global__ void ntx_fin(const float* __restrict__ a, const float* __restrict__ b,
                        const float* __restrict__ L, float* __restrict__ partial) {
  int row  = blockIdx.x * 4 + (threadIdx.x >> 6);
  int lane = threadIdx.x & 63;
  const float* x = (row < B_) ? (a + (size_t)row * D_) : (b + (size_t)(row - B_) * D_);
  int p = (row < B_) ? row + B_ : row - B_;
  const float* y = (p < B_) ? (a + (size_t)p * D_) : (b + (size_t)(p - B_) * D_);
  const float4* x4 = (const float4*)(x + lane * 8);
  const float4* y4 = (const float4*)(y + lane * 8);
  float4 xa = x4[0], xb = x4[1], ya = y4[0], yb = y4[1];
  float s = xa.x * ya.x + xa.y * ya.y + xa.z * ya.z + xa.w * ya.w
          + xb.x * yb.x + xb.y * yb.y + xb.z * yb.z + xb.w * yb.w;
#pragma unroll
  for (int off = 1; off < 64; off <<= 1) s += __shfl_xor(s, off);
  __shared__ float sm[4];
  if (lane == 0) sm[threadIdx.x >> 6] = __logf(L[row]) - s * INV_T;
  __syncthreads();
  if (threadIdx.x == 0) partial[blockIdx.x] = sm[0] + sm[1] + sm[2] + sm[3];
}

// Kernel 4: reduce 2048 partials -> mean (single block, deterministic order)
__global__ void ntx_fin2(const float* __restrict__ partial, float* __restrict__ out) {
  int t = threadIdx.x;
  float s = 0.0f;
#pragma unroll
  for (int k = 0; k < 8; ++k) s += partial[t + k * 256];
#pragma unroll
  for (int off = 1; off < 64; off <<= 1) s += __shfl_xor(s, off);
  __shared__ float sm[4];
  if ((t & 63) == 0) sm[t >> 6] = s;
  __syncthreads();
  if (t == 0) out[0] = (sm[0] + sm[1] + sm[2] + sm[3]) * (1.0f / TB_);
}

// ---------------------------------------------------------------------------
extern "C" void kernel_launch(void* const* d_in, const int* in_sizes, int n_in,
                              void* d_out, int out_size, void* d_ws, size_t ws_size,
                              hipStream_t stream) {
  const float* e1 = (const float*)d_in[0];
  const float* e2 = (const float*)d_in[1];
  float* out = (float*)d_out;
  unsigned short* E = (unsigned short*)d_ws;                        // 8 MB bf16
  float* L   = (float*)((char*)d_ws + (size_t)TB_ * D_ * 2);        // 32 KB
  float* par = L + TB_;                                             // 8 KB

  ntx_prep<<<2048, 256, 0, stream>>>(e1, e2, E, L);
  ntx_sim<<<NTRI, 256, 0, stream>>>(E, L);
  ntx_fin<<<TB_ / 4, 256, 0, stream>>>(e1, e2, L, par);
  ntx_fin2<<<1, 256, 0, stream>>>(par, out);
}